// Round 15
// baseline (1092.658 us; speedup 1.0000x reference)
//
#include <hip/hip_runtime.h>

#define U_CNT 100000
#define I_CNT 50000
#define N_CNT 150000
#define NNZ_CNT 3200000
#define EMB 64

// LOCKED correctness recipe (R9-R14 forensics):
//  - spmm: per-row FMA chain acc = fmaf(v_e, x_e, acc), ascending edges.
//    (Reference = XLA-CPU scatter-add lowered via llvm.fmuladd -> CPU FMA.
//     R9/R10 passed identically because hipcc CONTRACTED their +/* to v_fmac;
//     R11/R12/R14's 2-row loop didn't contract -> flips. Explicit fmaf makes
//     the bits structure-independent.)
//  - h path f64 (R10 op sequence), recomputed in apply (R13-proven).
//  - stats: f64 atomics, any order/grid (R12/R14 re-proved harmless).

__global__ void init_ego_kernel(const float* __restrict__ ue, const float* __restrict__ ie,
                                float* __restrict__ ego) {
  const int total = N_CNT * EMB, ucnt = U_CNT * EMB;
  for (int i = blockIdx.x * blockDim.x + threadIdx.x; i < total; i += gridDim.x * blockDim.x)
    ego[i] = (i < ucnt) ? ue[i] : ie[i - ucnt];
}

__global__ void build_row_ptr_kernel(const int* __restrict__ rows, int* __restrict__ rp) {
  int r = blockIdx.x * blockDim.x + threadIdx.x;
  if (r > N_CNT) return;
  int lo = 0, hi = NNZ_CNT;
  while (lo < hi) { int mid = (lo + hi) >> 1; if (rows[mid] < r) lo = mid + 1; else hi = mid; }
  rp[r] = lo;
}

__global__ void zero_stats_kernel(double* __restrict__ stats) {
  stats[threadIdx.x] = 0.0;
  stats[256 + threadIdx.x] = 0.0;  // both buffers
}

// spmm: 2 rows/wave, 8-deep load batches (16 outstanding gathers),
// per-row explicit fmaf chain in ascending edge order (bit-locked semantics).
__global__ __launch_bounds__(256) void spmm_kernel(const float* __restrict__ x, float* __restrict__ y,
                            const int* __restrict__ rp, const int* __restrict__ cols,
                            const float* __restrict__ vals) {
  const int wave = threadIdx.x >> 6, lane = threadIdx.x & 63;
  const int rowA = blockIdx.x * 8 + (wave << 1);
  if (rowA >= N_CNT) return;
  const int rowB = rowA + 1;  // rowA even, N even -> rowB < N_CNT
  int eA = rp[rowA];
  const int endA = rp[rowB];
  int eB = endA;
  const int endB = rp[rowB + 1];
  float accA = 0.f, accB = 0.f;
  while (endA - eA >= 8 && endB - eB >= 8) {
    float va[8], xa[8], vb[8], xb[8];
    #pragma unroll
    for (int j = 0; j < 8; ++j) {
      const int c = cols[eA + j];
      va[j] = vals[eA + j];
      xa[j] = x[(size_t)c * EMB + lane];
    }
    #pragma unroll
    for (int j = 0; j < 8; ++j) {
      const int c = cols[eB + j];
      vb[j] = vals[eB + j];
      xb[j] = x[(size_t)c * EMB + lane];
    }
    #pragma unroll
    for (int j = 0; j < 8; ++j) accA = fmaf(va[j], xa[j], accA);
    #pragma unroll
    for (int j = 0; j < 8; ++j) accB = fmaf(vb[j], xb[j], accB);
    eA += 8; eB += 8;
  }
  while (endA - eA >= 8) {
    float vv[8], xv[8];
    #pragma unroll
    for (int j = 0; j < 8; ++j) {
      const int c = cols[eA + j];
      vv[j] = vals[eA + j];
      xv[j] = x[(size_t)c * EMB + lane];
    }
    #pragma unroll
    for (int j = 0; j < 8; ++j) accA = fmaf(vv[j], xv[j], accA);
    eA += 8;
  }
  while (endB - eB >= 8) {
    float vv[8], xv[8];
    #pragma unroll
    for (int j = 0; j < 8; ++j) {
      const int c = cols[eB + j];
      vv[j] = vals[eB + j];
      xv[j] = x[(size_t)c * EMB + lane];
    }
    #pragma unroll
    for (int j = 0; j < 8; ++j) accB = fmaf(vv[j], xv[j], accB);
    eB += 8;
  }
  for (; eA < endA; ++eA)
    accA = fmaf(vals[eA], x[(size_t)cols[eA] * EMB + lane], accA);
  for (; eB < endB; ++eB)
    accB = fmaf(vals[eB], x[(size_t)cols[eB] * EMB + lane], accB);
  y[(size_t)rowA * EMB + lane] = accA;
  y[(size_t)rowB * EMB + lane] = accB;
}

#define GU 2048
#define GI 1024

// R10's gemv op sequence (f32 LDS staging, in-loop converts, single f64 fma
// chain), no h store: per-column sum/sumsq only.
__global__ __launch_bounds__(256) void stats_kernel(const float* __restrict__ y,
                                  const float* __restrict__ Wu, const float* __restrict__ bu,
                                  const float* __restrict__ Wi, const float* __restrict__ bi,
                                  double* __restrict__ stats) {
  __shared__ float ysh[4][EMB];
  __shared__ double red[4][EMB];
  const int wave = threadIdx.x >> 6, lane = threadIdx.x & 63;
  const bool isU = blockIdx.x < GU;
  const int blk = isU ? blockIdx.x : blockIdx.x - GU;
  const int nblk = isU ? GU : GI;
  const int nrows = isU ? U_CNT : I_CNT;
  const float* Wf = isU ? Wu : Wi;
  const float* bf = isU ? bu : bi;
  const float* yp = isU ? y : (y + (size_t)U_CNT * EMB);
  double* sum_out = stats + (isU ? 0 : 128);
  double* sq_out = sum_out + 64;

  float w[EMB];
  #pragma unroll
  for (int k = 0; k < EMB; k += 4) {
    float4 t = *(const float4*)&Wf[lane * EMB + k];
    w[k] = t.x; w[k+1] = t.y; w[k+2] = t.z; w[k+3] = t.w;
  }
  const double bj = (double)bf[lane];
  double s = 0.0, q = 0.0;
  for (int r = blk * 4 + wave; r < nrows; r += nblk * 4) {
    ysh[wave][lane] = yp[(size_t)r * EMB + lane];
    double acc = 0.0;
    #pragma unroll
    for (int k = 0; k < EMB; ++k) acc = fma((double)ysh[wave][k], (double)w[k], acc);
    double h0 = acc + bj;
    h0 = (h0 >= 0.0) ? h0 : 0.01 * h0;
    s += h0;
    q = fma(h0, h0, q);
  }
  red[wave][lane] = s;
  __syncthreads();
  if (wave == 0)
    atomicAdd(&sum_out[lane], red[0][lane] + red[1][lane] + red[2][lane] + red[3][lane]);
  __syncthreads();
  red[wave][lane] = q;
  __syncthreads();
  if (wave == 0)
    atomicAdd(&sq_out[lane], red[0][lane] + red[1][lane] + red[2][lane] + red[3][lane]);
}

// apply: recompute h (identical op sequence), inline mu/R, R10 noise math.
// Block 0 zeroes next layer's stats buffer.
__global__ __launch_bounds__(256) void apply_kernel(const float* __restrict__ y,
                             float* __restrict__ ego, float* __restrict__ out_final,
                             float* __restrict__ out_cl,
                             const double* __restrict__ stats, double* __restrict__ stats_next,
                             const float* __restrict__ Wu, const float* __restrict__ bu,
                             const float* __restrict__ gu, const float* __restrict__ btu,
                             const float* __restrict__ Wi, const float* __restrict__ bi,
                             const float* __restrict__ gi, const float* __restrict__ bti,
                             int layer) {
  __shared__ float ysh[4][EMB];
  const int wave = threadIdx.x >> 6, lane = threadIdx.x & 63;
  if (blockIdx.x == 0) stats_next[threadIdx.x] = 0.0;
  const bool isU = blockIdx.x < GU;
  const int blk = isU ? blockIdx.x : blockIdx.x - GU;
  const int nblk = isU ? GU : GI;
  const int nrows = isU ? U_CNT : I_CNT;
  const size_t off = isU ? 0 : (size_t)U_CNT * EMB;
  const float* Wf = isU ? Wu : Wi;
  const float* bf = isU ? bu : bi;

  float w[EMB];
  #pragma unroll
  for (int k = 0; k < EMB; k += 4) {
    float4 t = *(const float4*)&Wf[lane * EMB + k];
    w[k] = t.x; w[k+1] = t.y; w[k+2] = t.z; w[k+3] = t.w;
  }
  const double bj = (double)bf[lane];
  const double cnt = isU ? (double)U_CNT : (double)I_CNT;
  const double S = stats[(isU ? 0 : 128) + lane];
  const double Q = stats[(isU ? 0 : 128) + 64 + lane];
  const double muj = S / cnt;
  double var = Q / cnt - muj * muj;
  if (var < 0.0) var = 0.0;
  const double Rj = 1.0 / sqrt(var + 1e-5);
  const double gj = (double)(isU ? gu[lane] : gi[lane]);
  const double btj = (double)(isU ? btu[lane] : bti[lane]);

  for (int r = blk * 4 + wave; r < nrows; r += nblk * 4) {
    const size_t o = off + (size_t)r * EMB + lane;
    const float yv = y[o];
    ysh[wave][lane] = yv;
    double acc = 0.0;
    #pragma unroll
    for (int k = 0; k < EMB; ++k) acc = fma((double)ysh[wave][k], (double)w[k], acc);
    double h0 = acc + bj;
    h0 = (h0 >= 0.0) ? h0 : 0.01 * h0;
    const double hn = ((h0 - muj) * Rj) * gj + btj;
    double ss = hn * hn;
    #pragma unroll
    for (int sh = 32; sh > 0; sh >>= 1) ss += __shfl_xor(ss, sh, 64);
    double nrm = sqrt(ss);
    if (nrm < 1e-12) nrm = 1e-12;
    const float noise = (float)(hn / nrm);
    const float sgn = (yv > 0.f) ? 1.f : ((yv < 0.f) ? -1.f : 0.f);
    const float t2 = __fmul_rn(__fmul_rn(sgn, noise), 0.1f);
    const float en = __fadd_rn(yv, t2);
    ego[o] = en;
    if (layer == 0) { out_final[o] = en; out_cl[o] = en; }
    else if (layer == 1) { out_final[o] = __fadd_rn(out_final[o], en); }
    else { out_final[o] = __fdiv_rn(__fadd_rn(out_final[o], en), 3.0f); }
  }
}

extern "C" void kernel_launch(void* const* d_in, const int* in_sizes, int n_in,
                              void* d_out, int out_size, void* d_ws, size_t ws_size,
                              hipStream_t stream) {
  const float* user_emb = (const float*)d_in[0];
  const float* item_emb = (const float*)d_in[1];
  const int* adj_rows = (const int*)d_in[2];
  const int* adj_cols = (const int*)d_in[3];
  const float* adj_vals = (const float*)d_in[4];
  const float* Wu = (const float*)d_in[5];
  const float* bu = (const float*)d_in[6];
  const float* gu = (const float*)d_in[7];
  const float* btu = (const float*)d_in[8];
  const float* Wi = (const float*)d_in[9];
  const float* bi = (const float*)d_in[10];
  const float* gi = (const float*)d_in[11];
  const float* bti = (const float*)d_in[12];
  float* out = (float*)d_out;

  float* ego = (float*)d_ws;                            // [N,64] f32
  float* y = ego + (size_t)N_CNT * EMB;                 // [N,64] f32
  double* stats = (double*)(y + (size_t)N_CNT * EMB);   // 2 x 256 f64 (double-buffered)
  int* rp = (int*)(stats + 512);                        // [N+1]

  float* out_final = out;                               // final [N,64] flat f32
  float* out_cl = out + (size_t)N_CNT * EMB;            // emb_cl [N,64] flat f32

  init_ego_kernel<<<2048, 256, 0, stream>>>(user_emb, item_emb, ego);
  build_row_ptr_kernel<<<(N_CNT + 1 + 255) / 256, 256, 0, stream>>>(adj_rows, rp);
  zero_stats_kernel<<<1, 256, 0, stream>>>(stats);

  for (int layer = 0; layer < 3; ++layer) {
    double* stats_cur = stats + (layer & 1) * 256;
    double* stats_next = stats + ((layer + 1) & 1) * 256;
    spmm_kernel<<<(N_CNT + 7) / 8, 256, 0, stream>>>(ego, y, rp, adj_cols, adj_vals);
    stats_kernel<<<GU + GI, 256, 0, stream>>>(y, Wu, bu, Wi, bi, stats_cur);
    apply_kernel<<<GU + GI, 256, 0, stream>>>(y, ego, out_final, out_cl,
                                              stats_cur, stats_next,
                                              Wu, bu, gu, btu, Wi, bi, gi, bti, layer);
  }
}

// Round 16
// 1007.094 us; speedup vs baseline: 1.0850x; 1.0850x over previous
//
#include <hip/hip_runtime.h>

#define U_CNT 100000
#define I_CNT 50000
#define N_CNT 150000
#define NNZ_CNT 3200000
#define EMB 64

// LOCKED correctness recipe (R9-R15 forensics):
//  - spmm: per-row chain acc = fmaf(v_e, x_e, acc), ascending edges (reference
//    = XLA-CPU scatter-add via llvm.fmuladd -> FMA). Structure-independent
//    (R15 proof) -> batching/row-count free to change.
//  - h path: f64, W*y dot as 4 independent f64 FMA chains combined
//    ((a0+a1)+(a2+a3))+bj (R11==R12 proved zero flips vs sequential), h stored
//    f64 (R10-proven), consumed by streaming apply (R10's exact noise math).
//  - stats: f64 atomics any order; finalize inline in apply (R13/R15-proven).

__global__ void init_ego_kernel(const float* __restrict__ ue, const float* __restrict__ ie,
                                float* __restrict__ ego) {
  const int total = N_CNT * EMB, ucnt = U_CNT * EMB;
  for (int i = blockIdx.x * blockDim.x + threadIdx.x; i < total; i += gridDim.x * blockDim.x)
    ego[i] = (i < ucnt) ? ue[i] : ie[i - ucnt];
}

__global__ void build_row_ptr_kernel(const int* __restrict__ rows, int* __restrict__ rp) {
  int r = blockIdx.x * blockDim.x + threadIdx.x;
  if (r > N_CNT) return;
  int lo = 0, hi = NNZ_CNT;
  while (lo < hi) { int mid = (lo + hi) >> 1; if (rows[mid] < r) lo = mid + 1; else hi = mid; }
  rp[r] = lo;
}

__global__ void zero_stats_kernel(double* __restrict__ stats) {
  stats[threadIdx.x] = 0.0;
  stats[256 + threadIdx.x] = 0.0;  // both buffers
}

// spmm: 4 rows/wave, 8-deep load batches (up to 32 outstanding gathers),
// per-row explicit fmaf chain in ascending edge order (bit-locked semantics).
#define LOAD8(ee, V, X)                                                      \
  _Pragma("unroll")                                                          \
  for (int j = 0; j < 8; ++j) {                                              \
    const int c = cols[ee + j];                                              \
    V[j] = vals[ee + j];                                                     \
    X[j] = x[(size_t)c * EMB + lane];                                        \
  }
#define FMA8(V, X, acc)                                                      \
  _Pragma("unroll")                                                          \
  for (int j = 0; j < 8; ++j) acc = fmaf(V[j], X[j], acc);
#define B8(ee, acc)                                                          \
  { float V[8], X[8]; LOAD8(ee, V, X) FMA8(V, X, acc) ee += 8; }

__global__ __launch_bounds__(256) void spmm_kernel(const float* __restrict__ x, float* __restrict__ y,
                            const int* __restrict__ rp, const int* __restrict__ cols,
                            const float* __restrict__ vals) {
  const int wave = threadIdx.x >> 6, lane = threadIdx.x & 63;
  const int row0 = blockIdx.x * 16 + (wave << 2);
  if (row0 >= N_CNT) return;   // N_CNT % 16 == 0 -> all 4 rows valid
  int eA = rp[row0];
  const int nA = rp[row0 + 1];
  int eB = nA;
  const int nB = rp[row0 + 2];
  int eC = nB;
  const int nC = rp[row0 + 3];
  int eD = nC;
  const int nD = rp[row0 + 4];
  float aA = 0.f, aB = 0.f, aC = 0.f, aD = 0.f;
  while (nA - eA >= 8 && nB - eB >= 8 && nC - eC >= 8 && nD - eD >= 8) {
    float VA[8], XA[8], VB[8], XB[8], VC[8], XC[8], VD[8], XD[8];
    LOAD8(eA, VA, XA)
    LOAD8(eB, VB, XB)
    LOAD8(eC, VC, XC)
    LOAD8(eD, VD, XD)
    FMA8(VA, XA, aA)
    FMA8(VB, XB, aB)
    FMA8(VC, XC, aC)
    FMA8(VD, XD, aD)
    eA += 8; eB += 8; eC += 8; eD += 8;
  }
  while (nA - eA >= 8) B8(eA, aA)
  while (nB - eB >= 8) B8(eB, aB)
  while (nC - eC >= 8) B8(eC, aC)
  while (nD - eD >= 8) B8(eD, aD)
  for (; eA < nA; ++eA) aA = fmaf(vals[eA], x[(size_t)cols[eA] * EMB + lane], aA);
  for (; eB < nB; ++eB) aB = fmaf(vals[eB], x[(size_t)cols[eB] * EMB + lane], aB);
  for (; eC < nC; ++eC) aC = fmaf(vals[eC], x[(size_t)cols[eC] * EMB + lane], aC);
  for (; eD < nD; ++eD) aD = fmaf(vals[eD], x[(size_t)cols[eD] * EMB + lane], aD);
  y[(size_t)row0 * EMB + lane] = aA;
  y[(size_t)(row0 + 1) * EMB + lane] = aB;
  y[(size_t)(row0 + 2) * EMB + lane] = aC;
  y[(size_t)(row0 + 3) * EMB + lane] = aD;
}

#define GU 2048
#define GI 1024

// f64 gemv (4 independent FMA chains, float4 LDS reads, exact converts) +
// leaky; STORES h (f64); per-column sum/sumsq via f64 atomics.
__global__ __launch_bounds__(256) void stats_kernel(const float* __restrict__ y, double* __restrict__ h,
                                  const float* __restrict__ Wu, const float* __restrict__ bu,
                                  const float* __restrict__ Wi, const float* __restrict__ bi,
                                  double* __restrict__ stats) {
  __shared__ float ysh[4][EMB];
  __shared__ double red[4][EMB];
  const int wave = threadIdx.x >> 6, lane = threadIdx.x & 63;
  const bool isU = blockIdx.x < GU;
  const int blk = isU ? blockIdx.x : blockIdx.x - GU;
  const int nblk = isU ? GU : GI;
  const int nrows = isU ? U_CNT : I_CNT;
  const float* Wf = isU ? Wu : Wi;
  const float* bf = isU ? bu : bi;
  const float* yp = isU ? y : (y + (size_t)U_CNT * EMB);
  double* hp = isU ? h : (h + (size_t)U_CNT * EMB);
  double* sum_out = stats + (isU ? 0 : 128);
  double* sq_out = sum_out + 64;

  float w[EMB];
  #pragma unroll
  for (int k = 0; k < EMB; k += 4) {
    float4 t = *(const float4*)&Wf[lane * EMB + k];
    w[k] = t.x; w[k+1] = t.y; w[k+2] = t.z; w[k+3] = t.w;
  }
  const double bj = (double)bf[lane];
  double s = 0.0, q = 0.0;
  for (int r = blk * 4 + wave; r < nrows; r += nblk * 4) {
    ysh[wave][lane] = yp[(size_t)r * EMB + lane];
    double a0 = 0.0, a1 = 0.0, a2 = 0.0, a3 = 0.0;
    #pragma unroll
    for (int k = 0; k < EMB; k += 4) {
      float4 y4 = *(const float4*)&ysh[wave][k];
      a0 = fma((double)y4.x, (double)w[k], a0);
      a1 = fma((double)y4.y, (double)w[k + 1], a1);
      a2 = fma((double)y4.z, (double)w[k + 2], a2);
      a3 = fma((double)y4.w, (double)w[k + 3], a3);
    }
    double h0 = ((a0 + a1) + (a2 + a3)) + bj;
    h0 = (h0 >= 0.0) ? h0 : 0.01 * h0;
    hp[(size_t)r * EMB + lane] = h0;
    s += h0;
    q = fma(h0, h0, q);
  }
  red[wave][lane] = s;
  __syncthreads();
  if (wave == 0)
    atomicAdd(&sum_out[lane], red[0][lane] + red[1][lane] + red[2][lane] + red[3][lane]);
  __syncthreads();
  red[wave][lane] = q;
  __syncthreads();
  if (wave == 0)
    atomicAdd(&sq_out[lane], red[0][lane] + red[1][lane] + red[2][lane] + red[3][lane]);
}

// Streaming apply: loads h (no gemv), inline mu/R, R10's exact noise math.
// Block 0 zeroes next layer's stats buffer.
__global__ __launch_bounds__(256) void apply_kernel(const float* __restrict__ y, const double* __restrict__ h,
                             float* __restrict__ ego, float* __restrict__ out_final,
                             float* __restrict__ out_cl,
                             const double* __restrict__ stats, double* __restrict__ stats_next,
                             const float* __restrict__ gu, const float* __restrict__ btu,
                             const float* __restrict__ gi, const float* __restrict__ bti,
                             int layer) {
  const int wave = threadIdx.x >> 6, lane = threadIdx.x & 63;
  if (blockIdx.x == 0) stats_next[threadIdx.x] = 0.0;
  const bool isU = blockIdx.x < GU;
  const int blk = isU ? blockIdx.x : blockIdx.x - GU;
  const int nblk = isU ? GU : GI;
  const int nrows = isU ? U_CNT : I_CNT;
  const size_t off = isU ? 0 : (size_t)U_CNT * EMB;
  const double cnt = isU ? (double)U_CNT : (double)I_CNT;
  const double S = stats[(isU ? 0 : 128) + lane];
  const double Q = stats[(isU ? 0 : 128) + 64 + lane];
  const double muj = S / cnt;
  double var = Q / cnt - muj * muj;
  if (var < 0.0) var = 0.0;
  const double Rj = 1.0 / sqrt(var + 1e-5);
  const double gj = (double)(isU ? gu[lane] : gi[lane]);
  const double btj = (double)(isU ? btu[lane] : bti[lane]);
  for (int r = blk * 4 + wave; r < nrows; r += nblk * 4) {
    const size_t o = off + (size_t)r * EMB + lane;
    const float yv = y[o];
    const double hv = h[o];
    const double hn = ((hv - muj) * Rj) * gj + btj;
    double ss = hn * hn;
    #pragma unroll
    for (int sh = 32; sh > 0; sh >>= 1) ss += __shfl_xor(ss, sh, 64);
    double nrm = sqrt(ss);
    if (nrm < 1e-12) nrm = 1e-12;
    const float noise = (float)(hn / nrm);
    const float sgn = (yv > 0.f) ? 1.f : ((yv < 0.f) ? -1.f : 0.f);
    const float t2 = __fmul_rn(__fmul_rn(sgn, noise), 0.1f);
    const float en = __fadd_rn(yv, t2);
    ego[o] = en;
    if (layer == 0) { out_final[o] = en; out_cl[o] = en; }
    else if (layer == 1) { out_final[o] = __fadd_rn(out_final[o], en); }
    else { out_final[o] = __fdiv_rn(__fadd_rn(out_final[o], en), 3.0f); }
  }
}

extern "C" void kernel_launch(void* const* d_in, const int* in_sizes, int n_in,
                              void* d_out, int out_size, void* d_ws, size_t ws_size,
                              hipStream_t stream) {
  const float* user_emb = (const float*)d_in[0];
  const float* item_emb = (const float*)d_in[1];
  const int* adj_rows = (const int*)d_in[2];
  const int* adj_cols = (const int*)d_in[3];
  const float* adj_vals = (const float*)d_in[4];
  const float* Wu = (const float*)d_in[5];
  const float* bu = (const float*)d_in[6];
  const float* gu = (const float*)d_in[7];
  const float* btu = (const float*)d_in[8];
  const float* Wi = (const float*)d_in[9];
  const float* bi = (const float*)d_in[10];
  const float* gi = (const float*)d_in[11];
  const float* bti = (const float*)d_in[12];
  float* out = (float*)d_out;

  float* ego = (float*)d_ws;                            // [N,64] f32
  float* y = ego + (size_t)N_CNT * EMB;                 // [N,64] f32
  double* h = (double*)(y + (size_t)N_CNT * EMB);       // [N,64] f64
  double* stats = h + (size_t)N_CNT * EMB;              // 2 x 256 f64 (double-buffered)
  int* rp = (int*)(stats + 512);                        // [N+1]

  float* out_final = out;                               // final [N,64] flat f32
  float* out_cl = out + (size_t)N_CNT * EMB;            // emb_cl [N,64] flat f32

  init_ego_kernel<<<2048, 256, 0, stream>>>(user_emb, item_emb, ego);
  build_row_ptr_kernel<<<(N_CNT + 1 + 255) / 256, 256, 0, stream>>>(adj_rows, rp);
  zero_stats_kernel<<<1, 256, 0, stream>>>(stats);

  for (int layer = 0; layer < 3; ++layer) {
    double* stats_cur = stats + (layer & 1) * 256;
    double* stats_next = stats + ((layer + 1) & 1) * 256;
    spmm_kernel<<<(N_CNT + 15) / 16, 256, 0, stream>>>(ego, y, rp, adj_cols, adj_vals);
    stats_kernel<<<GU + GI, 256, 0, stream>>>(y, h, Wu, bu, Wi, bi, stats_cur);
    apply_kernel<<<GU + GI, 256, 0, stream>>>(y, h, ego, out_final, out_cl,
                                              stats_cur, stats_next,
                                              gu, btu, gi, bti, layer);
  }
}

// Round 17
// 816.215 us; speedup vs baseline: 1.3387x; 1.2339x over previous
//
#include <hip/hip_runtime.h>

#define U_CNT 100000
#define I_CNT 50000
#define N_CNT 150000
#define NNZ_CNT 3200000
#define EMB 64

// LOCKED correctness recipe (R9-R16 forensics):
//  - spmm: per-row chain acc = fmaf(v_e, x_e, acc), ascending edges (reference
//    = XLA-CPU scatter-add via llvm.fmuladd -> FMA). Structure-independent
//    (R15/R16 proof). PERF RULE: keep VGPR <= 64 (R16: 68 VGPR halved
//    occupancy, 135->208us).
//  - h path: f64 gemv as 4 independent FMA chains ((a0+a1)+(a2+a3))+bj,
//    h stored f64, streaming apply (all R16-proven).
//  - stats: f64 atomics any order; mu/R inline in apply; double-buffered.
// R17 = R15's spmm + R16's stats + R16's apply, verbatim composition.

__global__ void init_ego_kernel(const float* __restrict__ ue, const float* __restrict__ ie,
                                float* __restrict__ ego) {
  const int total = N_CNT * EMB, ucnt = U_CNT * EMB;
  for (int i = blockIdx.x * blockDim.x + threadIdx.x; i < total; i += gridDim.x * blockDim.x)
    ego[i] = (i < ucnt) ? ue[i] : ie[i - ucnt];
}

__global__ void build_row_ptr_kernel(const int* __restrict__ rows, int* __restrict__ rp) {
  int r = blockIdx.x * blockDim.x + threadIdx.x;
  if (r > N_CNT) return;
  int lo = 0, hi = NNZ_CNT;
  while (lo < hi) { int mid = (lo + hi) >> 1; if (rows[mid] < r) lo = mid + 1; else hi = mid; }
  rp[r] = lo;
}

__global__ void zero_stats_kernel(double* __restrict__ stats) {
  stats[threadIdx.x] = 0.0;
  stats[256 + threadIdx.x] = 0.0;  // both buffers
}

// spmm (R15 verbatim): 2 rows/wave, 8-deep load batches (16 outstanding),
// per-row explicit fmaf chain in ascending edge order.
__global__ __launch_bounds__(256) void spmm_kernel(const float* __restrict__ x, float* __restrict__ y,
                            const int* __restrict__ rp, const int* __restrict__ cols,
                            const float* __restrict__ vals) {
  const int wave = threadIdx.x >> 6, lane = threadIdx.x & 63;
  const int rowA = blockIdx.x * 8 + (wave << 1);
  if (rowA >= N_CNT) return;
  const int rowB = rowA + 1;  // rowA even, N even -> rowB < N_CNT
  int eA = rp[rowA];
  const int endA = rp[rowB];
  int eB = endA;
  const int endB = rp[rowB + 1];
  float accA = 0.f, accB = 0.f;
  while (endA - eA >= 8 && endB - eB >= 8) {
    float va[8], xa[8], vb[8], xb[8];
    #pragma unroll
    for (int j = 0; j < 8; ++j) {
      const int c = cols[eA + j];
      va[j] = vals[eA + j];
      xa[j] = x[(size_t)c * EMB + lane];
    }
    #pragma unroll
    for (int j = 0; j < 8; ++j) {
      const int c = cols[eB + j];
      vb[j] = vals[eB + j];
      xb[j] = x[(size_t)c * EMB + lane];
    }
    #pragma unroll
    for (int j = 0; j < 8; ++j) accA = fmaf(va[j], xa[j], accA);
    #pragma unroll
    for (int j = 0; j < 8; ++j) accB = fmaf(vb[j], xb[j], accB);
    eA += 8; eB += 8;
  }
  while (endA - eA >= 8) {
    float vv[8], xv[8];
    #pragma unroll
    for (int j = 0; j < 8; ++j) {
      const int c = cols[eA + j];
      vv[j] = vals[eA + j];
      xv[j] = x[(size_t)c * EMB + lane];
    }
    #pragma unroll
    for (int j = 0; j < 8; ++j) accA = fmaf(vv[j], xv[j], accA);
    eA += 8;
  }
  while (endB - eB >= 8) {
    float vv[8], xv[8];
    #pragma unroll
    for (int j = 0; j < 8; ++j) {
      const int c = cols[eB + j];
      vv[j] = vals[eB + j];
      xv[j] = x[(size_t)c * EMB + lane];
    }
    #pragma unroll
    for (int j = 0; j < 8; ++j) accB = fmaf(vv[j], xv[j], accB);
    eB += 8;
  }
  for (; eA < endA; ++eA)
    accA = fmaf(vals[eA], x[(size_t)cols[eA] * EMB + lane], accA);
  for (; eB < endB; ++eB)
    accB = fmaf(vals[eB], x[(size_t)cols[eB] * EMB + lane], accB);
  y[(size_t)rowA * EMB + lane] = accA;
  y[(size_t)rowB * EMB + lane] = accB;
}

#define GU 2048
#define GI 1024

// stats (R16 verbatim): f64 gemv (4 chains, float4 LDS reads) + leaky;
// stores h (f64); per-column sum/sumsq via f64 atomics.
__global__ __launch_bounds__(256) void stats_kernel(const float* __restrict__ y, double* __restrict__ h,
                                  const float* __restrict__ Wu, const float* __restrict__ bu,
                                  const float* __restrict__ Wi, const float* __restrict__ bi,
                                  double* __restrict__ stats) {
  __shared__ float ysh[4][EMB];
  __shared__ double red[4][EMB];
  const int wave = threadIdx.x >> 6, lane = threadIdx.x & 63;
  const bool isU = blockIdx.x < GU;
  const int blk = isU ? blockIdx.x : blockIdx.x - GU;
  const int nblk = isU ? GU : GI;
  const int nrows = isU ? U_CNT : I_CNT;
  const float* Wf = isU ? Wu : Wi;
  const float* bf = isU ? bu : bi;
  const float* yp = isU ? y : (y + (size_t)U_CNT * EMB);
  double* hp = isU ? h : (h + (size_t)U_CNT * EMB);
  double* sum_out = stats + (isU ? 0 : 128);
  double* sq_out = sum_out + 64;

  float w[EMB];
  #pragma unroll
  for (int k = 0; k < EMB; k += 4) {
    float4 t = *(const float4*)&Wf[lane * EMB + k];
    w[k] = t.x; w[k+1] = t.y; w[k+2] = t.z; w[k+3] = t.w;
  }
  const double bj = (double)bf[lane];
  double s = 0.0, q = 0.0;
  for (int r = blk * 4 + wave; r < nrows; r += nblk * 4) {
    ysh[wave][lane] = yp[(size_t)r * EMB + lane];
    double a0 = 0.0, a1 = 0.0, a2 = 0.0, a3 = 0.0;
    #pragma unroll
    for (int k = 0; k < EMB; k += 4) {
      float4 y4 = *(const float4*)&ysh[wave][k];
      a0 = fma((double)y4.x, (double)w[k], a0);
      a1 = fma((double)y4.y, (double)w[k + 1], a1);
      a2 = fma((double)y4.z, (double)w[k + 2], a2);
      a3 = fma((double)y4.w, (double)w[k + 3], a3);
    }
    double h0 = ((a0 + a1) + (a2 + a3)) + bj;
    h0 = (h0 >= 0.0) ? h0 : 0.01 * h0;
    hp[(size_t)r * EMB + lane] = h0;
    s += h0;
    q = fma(h0, h0, q);
  }
  red[wave][lane] = s;
  __syncthreads();
  if (wave == 0)
    atomicAdd(&sum_out[lane], red[0][lane] + red[1][lane] + red[2][lane] + red[3][lane]);
  __syncthreads();
  red[wave][lane] = q;
  __syncthreads();
  if (wave == 0)
    atomicAdd(&sq_out[lane], red[0][lane] + red[1][lane] + red[2][lane] + red[3][lane]);
}

// apply (R16 verbatim): streaming, inline mu/R, R10's exact noise math.
// Block 0 zeroes next layer's stats buffer.
__global__ __launch_bounds__(256) void apply_kernel(const float* __restrict__ y, const double* __restrict__ h,
                             float* __restrict__ ego, float* __restrict__ out_final,
                             float* __restrict__ out_cl,
                             const double* __restrict__ stats, double* __restrict__ stats_next,
                             const float* __restrict__ gu, const float* __restrict__ btu,
                             const float* __restrict__ gi, const float* __restrict__ bti,
                             int layer) {
  const int wave = threadIdx.x >> 6, lane = threadIdx.x & 63;
  if (blockIdx.x == 0) stats_next[threadIdx.x] = 0.0;
  const bool isU = blockIdx.x < GU;
  const int blk = isU ? blockIdx.x : blockIdx.x - GU;
  const int nblk = isU ? GU : GI;
  const int nrows = isU ? U_CNT : I_CNT;
  const size_t off = isU ? 0 : (size_t)U_CNT * EMB;
  const double cnt = isU ? (double)U_CNT : (double)I_CNT;
  const double S = stats[(isU ? 0 : 128) + lane];
  const double Q = stats[(isU ? 0 : 128) + 64 + lane];
  const double muj = S / cnt;
  double var = Q / cnt - muj * muj;
  if (var < 0.0) var = 0.0;
  const double Rj = 1.0 / sqrt(var + 1e-5);
  const double gj = (double)(isU ? gu[lane] : gi[lane]);
  const double btj = (double)(isU ? btu[lane] : bti[lane]);
  for (int r = blk * 4 + wave; r < nrows; r += nblk * 4) {
    const size_t o = off + (size_t)r * EMB + lane;
    const float yv = y[o];
    const double hv = h[o];
    const double hn = ((hv - muj) * Rj) * gj + btj;
    double ss = hn * hn;
    #pragma unroll
    for (int sh = 32; sh > 0; sh >>= 1) ss += __shfl_xor(ss, sh, 64);
    double nrm = sqrt(ss);
    if (nrm < 1e-12) nrm = 1e-12;
    const float noise = (float)(hn / nrm);
    const float sgn = (yv > 0.f) ? 1.f : ((yv < 0.f) ? -1.f : 0.f);
    const float t2 = __fmul_rn(__fmul_rn(sgn, noise), 0.1f);
    const float en = __fadd_rn(yv, t2);
    ego[o] = en;
    if (layer == 0) { out_final[o] = en; out_cl[o] = en; }
    else if (layer == 1) { out_final[o] = __fadd_rn(out_final[o], en); }
    else { out_final[o] = __fdiv_rn(__fadd_rn(out_final[o], en), 3.0f); }
  }
}

extern "C" void kernel_launch(void* const* d_in, const int* in_sizes, int n_in,
                              void* d_out, int out_size, void* d_ws, size_t ws_size,
                              hipStream_t stream) {
  const float* user_emb = (const float*)d_in[0];
  const float* item_emb = (const float*)d_in[1];
  const int* adj_rows = (const int*)d_in[2];
  const int* adj_cols = (const int*)d_in[3];
  const float* adj_vals = (const float*)d_in[4];
  const float* Wu = (const float*)d_in[5];
  const float* bu = (const float*)d_in[6];
  const float* gu = (const float*)d_in[7];
  const float* btu = (const float*)d_in[8];
  const float* Wi = (const float*)d_in[9];
  const float* bi = (const float*)d_in[10];
  const float* gi = (const float*)d_in[11];
  const float* bti = (const float*)d_in[12];
  float* out = (float*)d_out;

  float* ego = (float*)d_ws;                            // [N,64] f32
  float* y = ego + (size_t)N_CNT * EMB;                 // [N,64] f32
  double* h = (double*)(y + (size_t)N_CNT * EMB);       // [N,64] f64
  double* stats = h + (size_t)N_CNT * EMB;              // 2 x 256 f64 (double-buffered)
  int* rp = (int*)(stats + 512);                        // [N+1]

  float* out_final = out;                               // final [N,64] flat f32
  float* out_cl = out + (size_t)N_CNT * EMB;            // emb_cl [N,64] flat f32

  init_ego_kernel<<<2048, 256, 0, stream>>>(user_emb, item_emb, ego);
  build_row_ptr_kernel<<<(N_CNT + 1 + 255) / 256, 256, 0, stream>>>(adj_rows, rp);
  zero_stats_kernel<<<1, 256, 0, stream>>>(stats);

  for (int layer = 0; layer < 3; ++layer) {
    double* stats_cur = stats + (layer & 1) * 256;
    double* stats_next = stats + ((layer + 1) & 1) * 256;
    spmm_kernel<<<(N_CNT + 7) / 8, 256, 0, stream>>>(ego, y, rp, adj_cols, adj_vals);
    stats_kernel<<<GU + GI, 256, 0, stream>>>(y, h, Wu, bu, Wi, bi, stats_cur);
    apply_kernel<<<GU + GI, 256, 0, stream>>>(y, h, ego, out_final, out_cl,
                                              stats_cur, stats_next,
                                              gu, btu, gi, bti, layer);
  }
}